// Round 1
// baseline (337.458 us; speedup 1.0000x reference)
//
#include <hip/hip_runtime.h>
#include <hip/hip_bf16.h>

typedef unsigned short u16;
typedef unsigned int u32;
typedef __attribute__((ext_vector_type(8))) __bf16 bf16x8;
typedef __attribute__((ext_vector_type(4))) float f32x4;

#define NROW 4096
#define DDIM 2048
#define NCLS 8192
#define MARGIN 0.3f
#define EPS_LS 0.1f
#define FLT_MAX_ 3.402823466e+38f

#define GLOBAL_AS __attribute__((address_space(1)))
#define LDS_AS __attribute__((address_space(3)))

__device__ __forceinline__ void gload_lds16(const void* g, void* l) {
    __builtin_amdgcn_global_load_lds((const GLOBAL_AS u32*)g, (LDS_AS u32*)l, 16, 0, 0);
}

__device__ __forceinline__ u16 f2bf(float f) {
    u32 b = __float_as_uint(f);
    u32 r = (b + 0x7FFFu + ((b >> 16) & 1u)) >> 16;   // RNE, inputs are finite
    return (u16)r;
}

// ---------------- prep: f32 -> bf16, row sqnorms, init ap/an sentinels ----
__global__ __launch_bounds__(256) void prep_kernel(
    const float* __restrict__ emb, u16* __restrict__ e16,
    float* __restrict__ xx, int* __restrict__ ap, int* __restrict__ an)
{
    int row = blockIdx.x, tid = threadIdx.x;
    const float4* p = (const float4*)(emb + (size_t)row * DDIM);
    float4 a = p[tid * 2], b = p[tid * 2 + 1];
    float s = a.x*a.x + a.y*a.y + a.z*a.z + a.w*a.w
            + b.x*b.x + b.y*b.y + b.z*b.z + b.w*b.w;

    uint4 pk;
    pk.x = (u32)f2bf(a.x) | ((u32)f2bf(a.y) << 16);
    pk.y = (u32)f2bf(a.z) | ((u32)f2bf(a.w) << 16);
    pk.z = (u32)f2bf(b.x) | ((u32)f2bf(b.y) << 16);
    pk.w = (u32)f2bf(b.z) | ((u32)f2bf(b.w) << 16);
    *(uint4*)&e16[(size_t)row * DDIM + tid * 8] = pk;

    #pragma unroll
    for (int o = 1; o < 64; o <<= 1) s += __shfl_xor(s, o);
    __shared__ float sred[4];
    if ((tid & 63) == 0) sred[tid >> 6] = s;
    __syncthreads();
    if (tid == 0) {
        xx[row] = sred[0] + sred[1] + sred[2] + sred[3];
        ap[row] = 0x80000000;           // INT_MIN sentinel for max
        an[row] = 0x7FFFFFFF;           // INT_MAX sentinel for min
    }
}

// ---------------- CE with label smoothing ---------------------------------
__global__ __launch_bounds__(256) void ce_kernel(
    const float* __restrict__ pred, const int* __restrict__ tgt,
    float* __restrict__ out)
{
    int row = blockIdx.x, tid = threadIdx.x;
    const float4* p = (const float4*)(pred + (size_t)row * NCLS);
    float4 v[8];
    #pragma unroll
    for (int i = 0; i < 8; ++i) v[i] = p[tid + i * 256];

    float mx = -FLT_MAX_, sm = 0.f;
    #pragma unroll
    for (int i = 0; i < 8; ++i) {
        mx = fmaxf(mx, fmaxf(fmaxf(v[i].x, v[i].y), fmaxf(v[i].z, v[i].w)));
        sm += v[i].x + v[i].y + v[i].z + v[i].w;
    }
    #pragma unroll
    for (int o = 1; o < 64; o <<= 1) {
        mx = fmaxf(mx, __shfl_xor(mx, o));
        sm += __shfl_xor(sm, o);
    }
    __shared__ float smx[4], ssm[4], sse[4];
    int w = tid >> 6;
    if ((tid & 63) == 0) { smx[w] = mx; ssm[w] = sm; }
    __syncthreads();
    mx = fmaxf(fmaxf(smx[0], smx[1]), fmaxf(smx[2], smx[3]));
    sm = ssm[0] + ssm[1] + ssm[2] + ssm[3];

    float es = 0.f;
    #pragma unroll
    for (int i = 0; i < 8; ++i) {
        es += expf(v[i].x - mx) + expf(v[i].y - mx)
            + expf(v[i].z - mx) + expf(v[i].w - mx);
    }
    #pragma unroll
    for (int o = 1; o < 64; o <<= 1) es += __shfl_xor(es, o);
    if ((tid & 63) == 0) sse[w] = es;
    __syncthreads();
    if (tid == 0) {
        es = sse[0] + sse[1] + sse[2] + sse[3];
        float lse = mx + logf(es);
        int t = tgt[row];
        float lt = pred[(size_t)row * NCLS + t];
        float loss = (1.0f - EPS_LS) * (lse - lt)
                   + EPS_LS * (lse - sm * (1.0f / NCLS));
        atomicAdd(out, loss * (1.0f / NROW));
    }
}

// ---------------- Gram + fused batch-hard mining --------------------------
// 128x128 tile, BK=64, 4 waves (2x2), 4x4 16x16x32 frags per wave.
// LDS staged via global_load_lds(16B) with pre-swizzled global source:
// phys slot s holds logical k-slot s ^ (row&7)  -> conflict-free ds_read_b128.
__global__ __launch_bounds__(256) void gram_kernel(
    const u16* __restrict__ e16, const float* __restrict__ xx,
    const int* __restrict__ tg, int* __restrict__ ap, int* __restrict__ an)
{
    __shared__ __align__(16) u16 lsA[128 * 64];
    __shared__ __align__(16) u16 lsB[128 * 64];

    int bid = blockIdx.x;
    int wg  = ((bid & 7) << 7) | (bid >> 3);   // XCD swizzle, 1024 % 8 == 0
    int tm  = wg >> 5, tn = wg & 31;
    int rowBase = tm * 128, colBase = tn * 128;

    int tid = threadIdx.x;
    int wid = tid >> 6, lane = tid & 63;
    int wm = wid >> 1, wn = wid & 1;

    f32x4 acc[4][4];
    #pragma unroll
    for (int i = 0; i < 4; ++i)
        #pragma unroll
        for (int j = 0; j < 4; ++j) acc[i][j] = (f32x4){0.f, 0.f, 0.f, 0.f};

    int srow = lane >> 3;      // row within 8-row staging chunk
    int sslot = lane & 7;      // physical 16B slot

    for (int kb = 0; kb < DDIM; kb += 64) {
        #pragma unroll
        for (int t = 0; t < 4; ++t) {
            int r0 = (wid * 4 + t) * 8;
            int r  = r0 + srow;
            int gsl = sslot ^ (r & 7);
            const u16* ga = &e16[(size_t)(rowBase + r) * DDIM + kb + gsl * 8];
            gload_lds16(ga, &lsA[r0 * 64]);
            const u16* gb = &e16[(size_t)(colBase + r) * DDIM + kb + gsl * 8];
            gload_lds16(gb, &lsB[r0 * 64]);
        }
        __syncthreads();   // compiler drains vmcnt before barrier

        #pragma unroll
        for (int h = 0; h < 2; ++h) {
            bf16x8 af[4], bfr[4];
            #pragma unroll
            for (int fm = 0; fm < 4; ++fm) {
                int row = wm * 64 + fm * 16 + (lane & 15);
                int sl = (h * 4 + (lane >> 4)) ^ (row & 7);
                af[fm] = *(const bf16x8*)&lsA[row * 64 + sl * 8];
            }
            #pragma unroll
            for (int fn = 0; fn < 4; ++fn) {
                int row = wn * 64 + fn * 16 + (lane & 15);
                int sl = (h * 4 + (lane >> 4)) ^ (row & 7);
                bfr[fn] = *(const bf16x8*)&lsB[row * 64 + sl * 8];
            }
            #pragma unroll
            for (int fm = 0; fm < 4; ++fm)
                #pragma unroll
                for (int fn = 0; fn < 4; ++fn)
                    acc[fm][fn] = __builtin_amdgcn_mfma_f32_16x16x32_bf16(
                        af[fm], bfr[fn], acc[fm][fn], 0, 0, 0);
        }
        __syncthreads();
    }

    // Epilogue: d2 = xx[r] + xx[c] - 2*dot, masked max/min over cols.
    float xc[4]; int tc[4];
    #pragma unroll
    for (int fn = 0; fn < 4; ++fn) {
        int gc = colBase + wn * 64 + fn * 16 + (lane & 15);
        xc[fn] = xx[gc];
        tc[fn] = tg[gc];
    }
    #pragma unroll
    for (int fm = 0; fm < 4; ++fm) {
        #pragma unroll
        for (int reg = 0; reg < 4; ++reg) {
            int gr = rowBase + wm * 64 + fm * 16 + (lane >> 4) * 4 + reg;
            float xr = xx[gr];
            int   tr = tg[gr];
            float cap = -FLT_MAX_, can = FLT_MAX_;
            #pragma unroll
            for (int fn = 0; fn < 4; ++fn) {
                int gc = colBase + wn * 64 + fn * 16 + (lane & 15);
                float d2 = xr + xc[fn] - 2.0f * acc[fm][fn][reg];
                d2 = fmaxf(d2, 0.0f);
                if (gr == gc) d2 = 0.0f;      // exact diagonal
                if (tr == tc[fn]) cap = fmaxf(cap, d2);
                else              can = fminf(can, d2);
            }
            #pragma unroll
            for (int o = 1; o < 16; o <<= 1) {
                cap = fmaxf(cap, __shfl_xor(cap, o));
                can = fminf(can, __shfl_xor(can, o));
            }
            if ((lane & 15) == 0) {
                atomicMax(&ap[gr], __float_as_int(cap));
                atomicMin(&an[gr], __float_as_int(can));
            }
        }
    }
}

// ---------------- finalize: sqrt, outputs, margin loss --------------------
__global__ __launch_bounds__(256) void final_kernel(
    const int* __restrict__ ap, const int* __restrict__ an,
    float* __restrict__ out)
{
    int i = blockIdx.x * 256 + threadIdx.x;
    float a2 = __int_as_float(ap[i]);
    float n2 = __int_as_float(an[i]);
    float av = sqrtf(fmaxf(a2, 1e-12f));
    float nv = sqrtf(fmaxf(n2, 1e-12f));
    out[2 + i] = av;
    out[2 + NROW + i] = nv;
    float t = fmaxf(av - nv + MARGIN, 0.0f);
    #pragma unroll
    for (int o = 1; o < 64; o <<= 1) t += __shfl_xor(t, o);
    __shared__ float sred[4];
    if ((threadIdx.x & 63) == 0) sred[threadIdx.x >> 6] = t;
    __syncthreads();
    if (threadIdx.x == 0)
        atomicAdd(out + 1, (sred[0] + sred[1] + sred[2] + sred[3]) * (1.0f / NROW));
}

extern "C" void kernel_launch(void* const* d_in, const int* in_sizes, int n_in,
                              void* d_out, int out_size, void* d_ws, size_t ws_size,
                              hipStream_t stream)
{
    const float* emb  = (const float*)d_in[0];
    const float* pred = (const float*)d_in[1];
    const int*   tgt  = (const int*)d_in[2];
    float* out = (float*)d_out;

    char* ws = (char*)d_ws;
    u16*   e16 = (u16*)ws;                                   // 16 MB
    float* xx  = (float*)(ws + (size_t)16 * 1024 * 1024);    // 16 KB
    int*   ap  = (int*)(ws + (size_t)16 * 1024 * 1024 + 16384);
    int*   an  = (int*)(ws + (size_t)16 * 1024 * 1024 + 32768);

    hipMemsetAsync(d_out, 0, 2 * sizeof(float), stream);     // zero the two scalars
    prep_kernel <<<NROW, 256, 0, stream>>>(emb, e16, xx, ap, an);
    ce_kernel   <<<NROW, 256, 0, stream>>>(pred, tgt, out);
    gram_kernel <<<1024, 256, 0, stream>>>(e16, xx, tgt, ap, an);
    final_kernel<<<NROW / 256, 256, 0, stream>>>(ap, an, out);
}

// Round 2
// 330.412 us; speedup vs baseline: 1.0213x; 1.0213x over previous
//
#include <hip/hip_runtime.h>
#include <hip/hip_bf16.h>

typedef unsigned short u16;
typedef unsigned int u32;
typedef __attribute__((ext_vector_type(8))) __bf16 bf16x8;
typedef __attribute__((ext_vector_type(4))) float f32x4;

#define NROW 4096
#define DDIM 2048
#define NCLS 8192
#define MARGIN 0.3f
#define EPS_LS 0.1f
#define FLT_MAX_ 3.402823466e+38f

#define GLOBAL_AS __attribute__((address_space(1)))
#define LDS_AS __attribute__((address_space(3)))

__device__ __forceinline__ void gload_lds16(const void* g, void* l) {
    __builtin_amdgcn_global_load_lds((const GLOBAL_AS u32*)g, (LDS_AS u32*)l, 16, 0, 0);
}

__device__ __forceinline__ u16 f2bf(float f) {
    u32 b = __float_as_uint(f);
    u32 r = (b + 0x7FFFu + ((b >> 16) & 1u)) >> 16;   // RNE, inputs are finite
    return (u16)r;
}

// ---------------- prep: f32 -> bf16, row sqnorms, init ap/an sentinels ----
__global__ __launch_bounds__(256) void prep_kernel(
    const float* __restrict__ emb, u16* __restrict__ e16,
    float* __restrict__ xx, int* __restrict__ ap, int* __restrict__ an)
{
    int row = blockIdx.x, tid = threadIdx.x;
    const float4* p = (const float4*)(emb + (size_t)row * DDIM);
    float4 a = p[tid * 2], b = p[tid * 2 + 1];
    float s = a.x*a.x + a.y*a.y + a.z*a.z + a.w*a.w
            + b.x*b.x + b.y*b.y + b.z*b.z + b.w*b.w;

    uint4 pk;
    pk.x = (u32)f2bf(a.x) | ((u32)f2bf(a.y) << 16);
    pk.y = (u32)f2bf(a.z) | ((u32)f2bf(a.w) << 16);
    pk.z = (u32)f2bf(b.x) | ((u32)f2bf(b.y) << 16);
    pk.w = (u32)f2bf(b.z) | ((u32)f2bf(b.w) << 16);
    *(uint4*)&e16[(size_t)row * DDIM + tid * 8] = pk;

    #pragma unroll
    for (int o = 1; o < 64; o <<= 1) s += __shfl_xor(s, o);
    __shared__ float sred[4];
    if ((tid & 63) == 0) sred[tid >> 6] = s;
    __syncthreads();
    if (tid == 0) {
        xx[row] = sred[0] + sred[1] + sred[2] + sred[3];
        ap[row] = 0x80000000;           // INT_MIN sentinel for max
        an[row] = 0x7FFFFFFF;           // INT_MAX sentinel for min
    }
}

// ---------------- CE with label smoothing ---------------------------------
__global__ __launch_bounds__(256) void ce_kernel(
    const float* __restrict__ pred, const int* __restrict__ tgt,
    float* __restrict__ out)
{
    int row = blockIdx.x, tid = threadIdx.x;
    const float4* p = (const float4*)(pred + (size_t)row * NCLS);
    float4 v[8];
    #pragma unroll
    for (int i = 0; i < 8; ++i) v[i] = p[tid + i * 256];

    float mx = -FLT_MAX_, sm = 0.f;
    #pragma unroll
    for (int i = 0; i < 8; ++i) {
        mx = fmaxf(mx, fmaxf(fmaxf(v[i].x, v[i].y), fmaxf(v[i].z, v[i].w)));
        sm += v[i].x + v[i].y + v[i].z + v[i].w;
    }
    #pragma unroll
    for (int o = 1; o < 64; o <<= 1) {
        mx = fmaxf(mx, __shfl_xor(mx, o));
        sm += __shfl_xor(sm, o);
    }
    __shared__ float smx[4], ssm[4], sse[4];
    int w = tid >> 6;
    if ((tid & 63) == 0) { smx[w] = mx; ssm[w] = sm; }
    __syncthreads();
    mx = fmaxf(fmaxf(smx[0], smx[1]), fmaxf(smx[2], smx[3]));
    sm = ssm[0] + ssm[1] + ssm[2] + ssm[3];

    float es = 0.f;
    #pragma unroll
    for (int i = 0; i < 8; ++i) {
        es += expf(v[i].x - mx) + expf(v[i].y - mx)
            + expf(v[i].z - mx) + expf(v[i].w - mx);
    }
    #pragma unroll
    for (int o = 1; o < 64; o <<= 1) es += __shfl_xor(es, o);
    if ((tid & 63) == 0) sse[w] = es;
    __syncthreads();
    if (tid == 0) {
        es = sse[0] + sse[1] + sse[2] + sse[3];
        float lse = mx + logf(es);
        int t = tgt[row];
        float lt = pred[(size_t)row * NCLS + t];
        float loss = (1.0f - EPS_LS) * (lse - lt)
                   + EPS_LS * (lse - sm * (1.0f / NCLS));
        atomicAdd(out, loss * (1.0f / NROW));
    }
}

// ---------------- Gram + fused batch-hard mining (symmetric) --------------
// Upper-triangular 128x128 tiles only (528 of 1024). Off-diagonal tiles mine
// BOTH axes from the same accumulators; diagonal tiles row-side only.
// LDS staged via global_load_lds(16B) with pre-swizzled global source:
// phys slot s holds logical k-slot s ^ (row&7)  -> conflict-free ds_read_b128.
__global__ __launch_bounds__(256) void gram_kernel(
    const u16* __restrict__ e16, const float* __restrict__ xx,
    const int* __restrict__ tg, int* __restrict__ ap, int* __restrict__ an)
{
    __shared__ __align__(16) u16 lsA[128 * 64];
    __shared__ __align__(16) u16 lsB[128 * 64];

    int bid = blockIdx.x;
    int wg  = (bid & 7) * 66 + (bid >> 3);     // XCD swizzle, 528 = 8*66
    // decode upper-triangular tile index: C(tm) = tm*(65-tm)/2
    int tm = (int)(32.5f - sqrtf(32.5f * 32.5f - 2.0f * (float)wg));
    if (tm < 0) tm = 0;
    while (tm < 31 && (tm + 1) * (65 - (tm + 1)) / 2 <= wg) ++tm;
    while (tm > 0 && tm * (65 - tm) / 2 > wg) --tm;
    int tn = tm + (wg - tm * (65 - tm) / 2);
    int rowBase = tm * 128, colBase = tn * 128;
    bool diag = (tm == tn);

    int tid = threadIdx.x;
    int wid = tid >> 6, lane = tid & 63;
    int wm = wid >> 1, wn = wid & 1;

    f32x4 acc[4][4];
    #pragma unroll
    for (int i = 0; i < 4; ++i)
        #pragma unroll
        for (int j = 0; j < 4; ++j) acc[i][j] = (f32x4){0.f, 0.f, 0.f, 0.f};

    int srow = lane >> 3;      // row within 8-row staging chunk
    int sslot = lane & 7;      // physical 16B slot

    for (int kb = 0; kb < DDIM; kb += 64) {
        #pragma unroll
        for (int t = 0; t < 4; ++t) {
            int r0 = (wid * 4 + t) * 8;
            int r  = r0 + srow;
            int gsl = sslot ^ (r & 7);
            const u16* ga = &e16[(size_t)(rowBase + r) * DDIM + kb + gsl * 8];
            gload_lds16(ga, &lsA[r0 * 64]);
            const u16* gb = &e16[(size_t)(colBase + r) * DDIM + kb + gsl * 8];
            gload_lds16(gb, &lsB[r0 * 64]);
        }
        __syncthreads();   // compiler drains vmcnt before barrier

        #pragma unroll
        for (int h = 0; h < 2; ++h) {
            bf16x8 af[4], bfr[4];
            #pragma unroll
            for (int fm = 0; fm < 4; ++fm) {
                int row = wm * 64 + fm * 16 + (lane & 15);
                int sl = (h * 4 + (lane >> 4)) ^ (row & 7);
                af[fm] = *(const bf16x8*)&lsA[row * 64 + sl * 8];
            }
            #pragma unroll
            for (int fn = 0; fn < 4; ++fn) {
                int row = wn * 64 + fn * 16 + (lane & 15);
                int sl = (h * 4 + (lane >> 4)) ^ (row & 7);
                bfr[fn] = *(const bf16x8*)&lsB[row * 64 + sl * 8];
            }
            #pragma unroll
            for (int fm = 0; fm < 4; ++fm)
                #pragma unroll
                for (int fn = 0; fn < 4; ++fn)
                    acc[fm][fn] = __builtin_amdgcn_mfma_f32_16x16x32_bf16(
                        af[fm], bfr[fn], acc[fm][fn], 0, 0, 0);
        }
        __syncthreads();
    }

    // Epilogue: d2 = xx[r] + xx[c] - 2*dot; row-side mining always,
    // col-side mining for off-diagonal tiles (covers the mirrored pairs).
    float xc[4]; int tc[4];
    float capc[4], canc[4];
    #pragma unroll
    for (int fn = 0; fn < 4; ++fn) {
        int gc = colBase + wn * 64 + fn * 16 + (lane & 15);
        xc[fn] = xx[gc];
        tc[fn] = tg[gc];
        capc[fn] = -FLT_MAX_;
        canc[fn] = FLT_MAX_;
    }
    #pragma unroll
    for (int fm = 0; fm < 4; ++fm) {
        #pragma unroll
        for (int reg = 0; reg < 4; ++reg) {
            int gr = rowBase + wm * 64 + fm * 16 + (lane >> 4) * 4 + reg;
            float xr = xx[gr];
            int   tr = tg[gr];
            float cap = -FLT_MAX_, can = FLT_MAX_;
            #pragma unroll
            for (int fn = 0; fn < 4; ++fn) {
                int gc = colBase + wn * 64 + fn * 16 + (lane & 15);
                float d2 = xr + xc[fn] - 2.0f * acc[fm][fn][reg];
                d2 = fmaxf(d2, 0.0f);
                if (gr == gc) d2 = 0.0f;      // exact diagonal (diag tiles)
                bool pos = (tr == tc[fn]);
                if (pos) { cap = fmaxf(cap, d2); capc[fn] = fmaxf(capc[fn], d2); }
                else     { can = fminf(can, d2); canc[fn] = fminf(canc[fn], d2); }
            }
            #pragma unroll
            for (int o = 1; o < 16; o <<= 1) {
                cap = fmaxf(cap, __shfl_xor(cap, o));
                can = fminf(can, __shfl_xor(can, o));
            }
            if ((lane & 15) == 0) {
                atomicMax(&ap[gr], __float_as_int(cap));
                atomicMin(&an[gr], __float_as_int(can));
            }
        }
    }
    if (!diag) {
        // col-side: reduce over the row axis (lane>>4 groups) per column
        #pragma unroll
        for (int fn = 0; fn < 4; ++fn) {
            float cap = capc[fn], can = canc[fn];
            cap = fmaxf(cap, __shfl_xor(cap, 16));
            can = fminf(can, __shfl_xor(can, 16));
            cap = fmaxf(cap, __shfl_xor(cap, 32));
            can = fminf(can, __shfl_xor(can, 32));
            if (lane < 16) {
                int gc = colBase + wn * 64 + fn * 16 + lane;
                atomicMax(&ap[gc], __float_as_int(cap));
                atomicMin(&an[gc], __float_as_int(can));
            }
        }
    }
}

// ---------------- finalize: sqrt, outputs, margin loss --------------------
__global__ __launch_bounds__(256) void final_kernel(
    const int* __restrict__ ap, const int* __restrict__ an,
    float* __restrict__ out)
{
    int i = blockIdx.x * 256 + threadIdx.x;
    float a2 = __int_as_float(ap[i]);
    float n2 = __int_as_float(an[i]);
    float av = sqrtf(fmaxf(a2, 1e-12f));
    float nv = sqrtf(fmaxf(n2, 1e-12f));
    out[2 + i] = av;
    out[2 + NROW + i] = nv;
    float t = fmaxf(av - nv + MARGIN, 0.0f);
    #pragma unroll
    for (int o = 1; o < 64; o <<= 1) t += __shfl_xor(t, o);
    __shared__ float sred[4];
    if ((threadIdx.x & 63) == 0) sred[threadIdx.x >> 6] = t;
    __syncthreads();
    if (threadIdx.x == 0)
        atomicAdd(out + 1, (sred[0] + sred[1] + sred[2] + sred[3]) * (1.0f / NROW));
}

extern "C" void kernel_launch(void* const* d_in, const int* in_sizes, int n_in,
                              void* d_out, int out_size, void* d_ws, size_t ws_size,
                              hipStream_t stream)
{
    const float* emb  = (const float*)d_in[0];
    const float* pred = (const float*)d_in[1];
    const int*   tgt  = (const int*)d_in[2];
    float* out = (float*)d_out;

    char* ws = (char*)d_ws;
    u16*   e16 = (u16*)ws;                                   // 16 MB
    float* xx  = (float*)(ws + (size_t)16 * 1024 * 1024);    // 16 KB
    int*   ap  = (int*)(ws + (size_t)16 * 1024 * 1024 + 16384);
    int*   an  = (int*)(ws + (size_t)16 * 1024 * 1024 + 32768);

    hipMemsetAsync(d_out, 0, 2 * sizeof(float), stream);     // zero the two scalars
    prep_kernel <<<NROW, 256, 0, stream>>>(emb, e16, xx, ap, an);
    ce_kernel   <<<NROW, 256, 0, stream>>>(pred, tgt, out);
    gram_kernel <<<528, 256, 0, stream>>>(e16, xx, tgt, ap, an);
    final_kernel<<<NROW / 256, 256, 0, stream>>>(ap, an, out);
}

// Round 3
// 294.669 us; speedup vs baseline: 1.1452x; 1.1213x over previous
//
#include <hip/hip_runtime.h>
#include <hip/hip_bf16.h>

typedef unsigned short u16;
typedef unsigned int u32;
typedef __attribute__((ext_vector_type(8))) __bf16 bf16x8;
typedef __attribute__((ext_vector_type(4))) float f32x4;

#define NROW 4096
#define DDIM 2048
#define NCLS 8192
#define MARGIN 0.3f
#define EPS_LS 0.1f
#define FLT_MAX_ 3.402823466e+38f

#define GLOBAL_AS __attribute__((address_space(1)))
#define LDS_AS __attribute__((address_space(3)))

__device__ __forceinline__ void gload_lds16(const void* g, void* l) {
    __builtin_amdgcn_global_load_lds((const GLOBAL_AS u32*)g, (LDS_AS u32*)l, 16, 0, 0);
}

__device__ __forceinline__ u16 f2bf(float f) {
    u32 b = __float_as_uint(f);
    u32 r = (b + 0x7FFFu + ((b >> 16) & 1u)) >> 16;   // RNE, inputs are finite
    return (u16)r;
}

// ---------------- prep: f32 -> bf16, row sqnorms, init ap/an sentinels ----
__global__ __launch_bounds__(256) void prep_kernel(
    const float* __restrict__ emb, u16* __restrict__ e16,
    float* __restrict__ xx, int* __restrict__ ap, int* __restrict__ an)
{
    int row = blockIdx.x, tid = threadIdx.x;
    const float4* p = (const float4*)(emb + (size_t)row * DDIM);
    float4 a = p[tid * 2], b = p[tid * 2 + 1];
    float s = a.x*a.x + a.y*a.y + a.z*a.z + a.w*a.w
            + b.x*b.x + b.y*b.y + b.z*b.z + b.w*b.w;

    uint4 pk;
    pk.x = (u32)f2bf(a.x) | ((u32)f2bf(a.y) << 16);
    pk.y = (u32)f2bf(a.z) | ((u32)f2bf(a.w) << 16);
    pk.z = (u32)f2bf(b.x) | ((u32)f2bf(b.y) << 16);
    pk.w = (u32)f2bf(b.z) | ((u32)f2bf(b.w) << 16);
    *(uint4*)&e16[(size_t)row * DDIM + tid * 8] = pk;

    #pragma unroll
    for (int o = 1; o < 64; o <<= 1) s += __shfl_xor(s, o);
    __shared__ float sred[4];
    if ((tid & 63) == 0) sred[tid >> 6] = s;
    __syncthreads();
    if (tid == 0) {
        xx[row] = sred[0] + sred[1] + sred[2] + sred[3];
        ap[row] = 0x80000000;           // INT_MIN sentinel for max
        an[row] = 0x7FFFFFFF;           // INT_MAX sentinel for min
    }
}

// ---------------- CE with label smoothing (device body) -------------------
__device__ __forceinline__ void ce_block(
    int row, const float* __restrict__ pred, const int* __restrict__ tgt,
    float* __restrict__ out, float* smem /* >= 12 floats */)
{
    int tid = threadIdx.x;
    const float4* p = (const float4*)(pred + (size_t)row * NCLS);
    float4 v[8];
    #pragma unroll
    for (int i = 0; i < 8; ++i) v[i] = p[tid + i * 256];

    float mx = -FLT_MAX_, sm = 0.f;
    #pragma unroll
    for (int i = 0; i < 8; ++i) {
        mx = fmaxf(mx, fmaxf(fmaxf(v[i].x, v[i].y), fmaxf(v[i].z, v[i].w)));
        sm += v[i].x + v[i].y + v[i].z + v[i].w;
    }
    #pragma unroll
    for (int o = 1; o < 64; o <<= 1) {
        mx = fmaxf(mx, __shfl_xor(mx, o));
        sm += __shfl_xor(sm, o);
    }
    float* smx = smem; float* ssm = smem + 4; float* sse = smem + 8;
    int w = tid >> 6;
    if ((tid & 63) == 0) { smx[w] = mx; ssm[w] = sm; }
    __syncthreads();
    mx = fmaxf(fmaxf(smx[0], smx[1]), fmaxf(smx[2], smx[3]));
    sm = ssm[0] + ssm[1] + ssm[2] + ssm[3];

    float es = 0.f;
    #pragma unroll
    for (int i = 0; i < 8; ++i) {
        es += expf(v[i].x - mx) + expf(v[i].y - mx)
            + expf(v[i].z - mx) + expf(v[i].w - mx);
    }
    #pragma unroll
    for (int o = 1; o < 64; o <<= 1) es += __shfl_xor(es, o);
    if ((tid & 63) == 0) sse[w] = es;
    __syncthreads();
    if (tid == 0) {
        es = sse[0] + sse[1] + sse[2] + sse[3];
        float lse = mx + logf(es);
        int t = tgt[row];
        float lt = pred[(size_t)row * NCLS + t];
        float loss = (1.0f - EPS_LS) * (lse - lt)
                   + EPS_LS * (lse - sm * (1.0f / NCLS));
        atomicAdd(out, loss * (1.0f / NROW));
    }
}

// ------- fused: triangular 64x128 Gram tiles + interleaved CE blocks ------
// Gram: row-blocks r (64 rows), col-blocks c (128 cols), tiles with c >= r>>1
// (1056 tiles) cover every unordered pair; mine BOTH axes (duplicates are
// harmless for max/min). LDS staged via global_load_lds(16B), pre-swizzled
// global source -> conflict-free ds_read_b128.
// CE blocks (4096) interleaved 4:1 so their HBM streaming hides under
// gram compute.
__global__ __launch_bounds__(256) void fused_kernel(
    const u16* __restrict__ e16, const float* __restrict__ xx,
    const int* __restrict__ tg, int* __restrict__ ap, int* __restrict__ an,
    const float* __restrict__ pred, float* __restrict__ out)
{
    __shared__ __align__(16) u16 lsA[64 * 64];
    __shared__ __align__(16) u16 lsB[128 * 64];
    __shared__ float cered[12];

    int bid = blockIdx.x;
    int q = bid / 5, rsel = bid - q * 5;
    if (rsel != 0) {
        int row = q * 4 + rsel - 1;
        if (row < NROW) ce_block(row, pred, tg, out, cered);
        return;
    }

    int g = q;                                   // gram block 0..1055
    int wg = ((g * 5) & 7) * 132 + (g >> 3);     // XCD-contiguous remap

    // decode wg -> (r,c): pair m covers [m(65-m), m(65-m)+2(32-m))
    float sq = sqrtf(4225.0f - 4.0f * (float)wg);
    int m = (int)((65.0f - sq) * 0.5f);
    if (m < 0) m = 0;
    if (m > 31) m = 31;
    while (m > 0 && m * (65 - m) > wg) --m;
    while (m < 31 && (m + 1) * (64 - m) <= wg) ++m;
    int off = wg - m * (65 - m);
    int half = 32 - m;
    int r = 2 * m + (off >= half ? 1 : 0);
    int c = m + (off >= half ? off - half : off);
    int rowBase = r * 64, colBase = c * 128;

    int tid = threadIdx.x;
    int wid = tid >> 6, lane = tid & 63;
    int wm = wid >> 1, wn = wid & 1;             // wave owns 32 rows x 64 cols

    f32x4 acc[2][4];
    #pragma unroll
    for (int i = 0; i < 2; ++i)
        #pragma unroll
        for (int j = 0; j < 4; ++j) acc[i][j] = (f32x4){0.f, 0.f, 0.f, 0.f};

    int srow = lane >> 3;      // row within 8-row staging chunk
    int sslot = lane & 7;      // physical 16B slot

    for (int kb = 0; kb < DDIM; kb += 64) {
        #pragma unroll
        for (int t = 0; t < 2; ++t) {            // A: 64 rows
            int r0 = wid * 16 + t * 8;
            int rr = r0 + srow;
            int gsl = sslot ^ (rr & 7);
            gload_lds16(&e16[(size_t)(rowBase + rr) * DDIM + kb + gsl * 8],
                        &lsA[r0 * 64]);
        }
        #pragma unroll
        for (int t = 0; t < 4; ++t) {            // B: 128 rows
            int r0 = wid * 32 + t * 8;
            int rr = r0 + srow;
            int gsl = sslot ^ (rr & 7);
            gload_lds16(&e16[(size_t)(colBase + rr) * DDIM + kb + gsl * 8],
                        &lsB[r0 * 64]);
        }
        __syncthreads();   // compiler drains vmcnt before barrier

        #pragma unroll
        for (int h = 0; h < 2; ++h) {
            bf16x8 af[2], bfr[4];
            #pragma unroll
            for (int fm = 0; fm < 2; ++fm) {
                int row = wm * 32 + fm * 16 + (lane & 15);
                int sl = (h * 4 + (lane >> 4)) ^ (row & 7);
                af[fm] = *(const bf16x8*)&lsA[row * 64 + sl * 8];
            }
            #pragma unroll
            for (int fn = 0; fn < 4; ++fn) {
                int row = wn * 64 + fn * 16 + (lane & 15);
                int sl = (h * 4 + (lane >> 4)) ^ (row & 7);
                bfr[fn] = *(const bf16x8*)&lsB[row * 64 + sl * 8];
            }
            #pragma unroll
            for (int fm = 0; fm < 2; ++fm)
                #pragma unroll
                for (int fn = 0; fn < 4; ++fn)
                    acc[fm][fn] = __builtin_amdgcn_mfma_f32_16x16x32_bf16(
                        af[fm], bfr[fn], acc[fm][fn], 0, 0, 0);
        }
        __syncthreads();
    }

    // Epilogue: d2 = xx[r]+xx[c]-2*dot; mine rows AND cols (dupes harmless).
    float xc[4]; int tc[4];
    float capc[4], canc[4];
    #pragma unroll
    for (int fn = 0; fn < 4; ++fn) {
        int gc = colBase + wn * 64 + fn * 16 + (lane & 15);
        xc[fn] = xx[gc];
        tc[fn] = tg[gc];
        capc[fn] = -FLT_MAX_;
        canc[fn] = FLT_MAX_;
    }
    #pragma unroll
    for (int fm = 0; fm < 2; ++fm) {
        #pragma unroll
        for (int reg = 0; reg < 4; ++reg) {
            int gr = rowBase + wm * 32 + fm * 16 + (lane >> 4) * 4 + reg;
            float xr = xx[gr];
            int   tr = tg[gr];
            float cap = -FLT_MAX_, can = FLT_MAX_;
            #pragma unroll
            for (int fn = 0; fn < 4; ++fn) {
                int gc = colBase + wn * 64 + fn * 16 + (lane & 15);
                float d2 = xr + xc[fn] - 2.0f * acc[fm][fn][reg];
                d2 = fmaxf(d2, 0.0f);
                if (gr == gc) d2 = 0.0f;      // exact diagonal
                bool pos = (tr == tc[fn]);
                if (pos) { cap = fmaxf(cap, d2); capc[fn] = fmaxf(capc[fn], d2); }
                else     { can = fminf(can, d2); canc[fn] = fminf(canc[fn], d2); }
            }
            #pragma unroll
            for (int o = 1; o < 16; o <<= 1) {
                cap = fmaxf(cap, __shfl_xor(cap, o));
                can = fminf(can, __shfl_xor(can, o));
            }
            if ((lane & 15) == 0) {
                atomicMax(&ap[gr], __float_as_int(cap));
                atomicMin(&an[gr], __float_as_int(can));
            }
        }
    }
    #pragma unroll
    for (int fn = 0; fn < 4; ++fn) {             // col side
        float cap = capc[fn], can = canc[fn];
        cap = fmaxf(cap, __shfl_xor(cap, 16));
        can = fminf(can, __shfl_xor(can, 16));
        cap = fmaxf(cap, __shfl_xor(cap, 32));
        can = fminf(can, __shfl_xor(can, 32));
        if (lane < 16) {
            int gc = colBase + wn * 64 + fn * 16 + lane;
            atomicMax(&ap[gc], __float_as_int(cap));
            atomicMin(&an[gc], __float_as_int(can));
        }
    }
}

// ---------------- finalize: sqrt, outputs, margin loss --------------------
__global__ __launch_bounds__(256) void final_kernel(
    const int* __restrict__ ap, const int* __restrict__ an,
    float* __restrict__ out)
{
    int i = blockIdx.x * 256 + threadIdx.x;
    float a2 = __int_as_float(ap[i]);
    float n2 = __int_as_float(an[i]);
    float av = sqrtf(fmaxf(a2, 1e-12f));
    float nv = sqrtf(fmaxf(n2, 1e-12f));
    out[2 + i] = av;
    out[2 + NROW + i] = nv;
    float t = fmaxf(av - nv + MARGIN, 0.0f);
    #pragma unroll
    for (int o = 1; o < 64; o <<= 1) t += __shfl_xor(t, o);
    __shared__ float sred[4];
    if ((threadIdx.x & 63) == 0) sred[threadIdx.x >> 6] = t;
    __syncthreads();
    if (threadIdx.x == 0)
        atomicAdd(out + 1, (sred[0] + sred[1] + sred[2] + sred[3]) * (1.0f / NROW));
}

extern "C" void kernel_launch(void* const* d_in, const int* in_sizes, int n_in,
                              void* d_out, int out_size, void* d_ws, size_t ws_size,
                              hipStream_t stream)
{
    const float* emb  = (const float*)d_in[0];
    const float* pred = (const float*)d_in[1];
    const int*   tgt  = (const int*)d_in[2];
    float* out = (float*)d_out;

    char* ws = (char*)d_ws;
    u16*   e16 = (u16*)ws;                                   // 16 MB
    float* xx  = (float*)(ws + (size_t)16 * 1024 * 1024);    // 16 KB
    int*   ap  = (int*)(ws + (size_t)16 * 1024 * 1024 + 16384);
    int*   an  = (int*)(ws + (size_t)16 * 1024 * 1024 + 32768);

    hipMemsetAsync(d_out, 0, 2 * sizeof(float), stream);     // zero the two scalars
    prep_kernel <<<NROW, 256, 0, stream>>>(emb, e16, xx, ap, an);
    fused_kernel<<<5280, 256, 0, stream>>>(e16, xx, tgt, ap, an, pred, out);
    final_kernel<<<NROW / 256, 256, 0, stream>>>(ap, an, out);
}